// Round 5
// baseline (474.485 us; speedup 1.0000x reference)
//
#include <hip/hip_runtime.h>
#include <cmath>

#define Bsz 4
#define Ssz 2048
#define Dsz 512
#define Hn 8
#define NBLK 512

typedef unsigned short u16;
typedef _Float16 f16;
typedef __attribute__((ext_vector_type(4))) _Float16 f16x4;
typedef __attribute__((ext_vector_type(8))) _Float16 f16x8;
typedef __attribute__((ext_vector_type(8))) unsigned short us8;
typedef __attribute__((ext_vector_type(4))) float f32x4;
typedef __attribute__((ext_vector_type(16))) float f32x16;

__device__ __forceinline__ void gl2lds16(const void* g, void* l) {
    __builtin_amdgcn_global_load_lds(
        (const __attribute__((address_space(1))) void*)g,
        (__attribute__((address_space(3))) void*)l, 16, 0, 0);
}

// ---- self-cleaning grid barrier: cnt returns to 0 each epoch, gen monotonic
// across launches/replays -> no host-side init needed. Device-scope atomics +
// threadfence handle cross-XCD L2 (writer-side wbl2, reader-side inv).
__device__ int g_cnt = 0;
__device__ int g_gen = 0;

__device__ __forceinline__ void grid_barrier() {
    __syncthreads();
    if (threadIdx.x == 0) {
        __threadfence();
        int gseen = __hip_atomic_load(&g_gen, __ATOMIC_RELAXED,
                                      __HIP_MEMORY_SCOPE_AGENT);
        int a = __hip_atomic_fetch_add(&g_cnt, 1, __ATOMIC_ACQ_REL,
                                       __HIP_MEMORY_SCOPE_AGENT);
        if (a == NBLK - 1) {
            __hip_atomic_store(&g_cnt, 0, __ATOMIC_RELAXED,
                               __HIP_MEMORY_SCOPE_AGENT);
            __hip_atomic_fetch_add(&g_gen, 1, __ATOMIC_RELEASE,
                                   __HIP_MEMORY_SCOPE_AGENT);
        } else {
            while (__hip_atomic_load(&g_gen, __ATOMIC_ACQUIRE,
                                     __HIP_MEMORY_SCOPE_AGENT) == gseen)
                __builtin_amdgcn_s_sleep(1);
        }
        __threadfence();
    }
    __syncthreads();
}

// ---- 128x128-tile fp16 MFMA GEMM as a 256-thread half-block device fn.
// Both halves of a 512-thread block run in lockstep (identical __syncthreads
// counts: 2/K-step x 8; epilogue counts match because pairs share colg/MODE).
// MODE 0: Q (x0.125) / K row-major f16; V -> packed V^T tiles. MODE 1: fp32.
template <int MODE>
__device__ __forceinline__ void gemm_tile(
    const int htid, const int vcol, const int rb, u16* halfsm,
    const f16* __restrict__ A, const f16* __restrict__ Bt,
    f16* o0, f16* o1, u16* o2v,
    const float* b0, const float* b1, const float* b2,
    float* ofp, const float* bias_f) {
    u16* As = halfsm;
    u16* Bs = halfsm + 128 * 64;
    const int colg0 = vcol * 128;
    const int row0 = rb * 128;
    const int w = htid >> 6, lane = htid & 63;
    const int nn = lane & 31, hh = lane >> 5;
    const int wr = w >> 1, wc = w & 1;

    f32x16 acc[2][2];
#pragma unroll
    for (int bi = 0; bi < 2; bi++)
#pragma unroll
        for (int bj = 0; bj < 2; bj++)
#pragma unroll
            for (int e = 0; e < 16; e++) acc[bi][bj][e] = 0.f;

    const f16* Ablk = A + (size_t)row0 * 512;
    const f16* Bblk = Bt + (size_t)colg0 * 512;

    for (int k0 = 0; k0 < 512; k0 += 64) {
        __syncthreads();
#pragma unroll
        for (int i = 0; i < 4; i++) {
            int p = htid + i * 256;          // 16B chunk id
            int m = p >> 3, kc = p & 7;
            int gk = ((kc ^ (m & 7)) << 3);  // XOR-swizzled k origin
            gl2lds16(Ablk + (size_t)m * 512 + k0 + gk, As + p * 8);
            gl2lds16(Bblk + (size_t)m * 512 + k0 + gk, Bs + p * 8);
        }
        __syncthreads();
#pragma unroll
        for (int t = 0; t < 4; t++) {        // four 32x32x16 k-steps
            f16x8 af[2], bfr[2];
#pragma unroll
            for (int bi = 0; bi < 2; bi++) {
                int r = wr * 64 + bi * 32 + nn;
                int ch = r * 8 + ((t * 2 + hh) ^ (r & 7));
                af[bi] = *(const f16x8*)(As + ch * 8);
            }
#pragma unroll
            for (int bj = 0; bj < 2; bj++) {
                int n = wc * 64 + bj * 32 + nn;
                int ch = n * 8 + ((t * 2 + hh) ^ (n & 7));
                bfr[bj] = *(const f16x8*)(Bs + ch * 8);
            }
#pragma unroll
            for (int bi = 0; bi < 2; bi++)
#pragma unroll
                for (int bj = 0; bj < 2; bj++)
                    acc[bi][bj] = __builtin_amdgcn_mfma_f32_32x32x16_f16(
                        af[bi], bfr[bj], acc[bi][bj], 0, 0, 0);
        }
    }

    // C/D mapping (m74/m101): col = nn, rowoff = (reg&3) + 8*(reg>>2) + 4*hh
    if (MODE == 0) {
        const int sel = colg0 >> 9;
        const int c0 = colg0 & 511;
        if (sel < 2) {                      // Q or K: plain row-major
            f16* outp = (sel == 0) ? o0 : o1;
            const float* bp = (sel == 0) ? b0 : b1;
            const float sc = (sel == 0) ? 0.125f : 1.0f;
#pragma unroll
            for (int bj = 0; bj < 2; bj++) {
                int col = c0 + wc * 64 + bj * 32 + nn;
                float bv = bp[col];
#pragma unroll
                for (int bi = 0; bi < 2; bi++)
#pragma unroll
                    for (int rg = 0; rg < 16; rg++) {
                        int row = row0 + wr * 64 + bi * 32 +
                                  (rg & 3) + 8 * (rg >> 2) + 4 * hh;
                        outp[(size_t)row * 512 + col] =
                            (f16)(fmaxf(acc[bi][bj][rg] + bv, 0.f) * sc);
                    }
            }
        } else {                            // V: LDS transpose -> packed V^T tiles
            const int hh_head = c0 >> 6;
            f16 (*T)[136] = (f16(*)[136])halfsm;   // 64 x 136 fp16 (17.4KB<=32KB)
            const int bb = row0 >> 11;
            const int t0 = (row0 & 2047) >> 6;
            __syncthreads();                // half's waves done reading As/Bs
#pragma unroll
            for (int ph = 0; ph < 2; ph++) {
                if (wc == ph) {
#pragma unroll
                    for (int bj = 0; bj < 2; bj++) {
                        int d = bj * 32 + nn;
                        float bv = b2[c0 + ph * 64 + d];
#pragma unroll
                        for (int bi = 0; bi < 2; bi++)
#pragma unroll
                            for (int rg = 0; rg < 16; rg++) {
                                int s = wr * 64 + bi * 32 +
                                        (rg & 3) + 8 * (rg >> 2) + 4 * hh;
                                T[d][s] = (f16)fmaxf(acc[bi][bj][rg] + bv, 0.f);
                            }
                    }
                }
                __syncthreads();
#pragma unroll
                for (int ii = 0; ii < 4; ii++) {
                    int oct = htid + ii * 256;       // 1024 octets = 2 tiles
                    int tt = oct >> 9, rem = oct & 511;
                    int d = rem >> 3, s8 = rem & 7;
                    us8 val = *(const us8*)(&T[d][tt * 64 + s8 * 8]);
                    size_t dst = (((size_t)((bb * 8 + hh_head + ph) * 32 + t0 + tt)) << 12)
                                 + d * 64 + s8 * 8;
                    *(us8*)(o2v + dst) = val;
                }
                __syncthreads();
            }
        }
    } else {
#pragma unroll
        for (int bj = 0; bj < 2; bj++) {
            int col = colg0 + wc * 64 + bj * 32 + nn;
            float bv = bias_f[col];
#pragma unroll
            for (int bi = 0; bi < 2; bi++)
#pragma unroll
                for (int rg = 0; rg < 16; rg++) {
                    int row = row0 + wr * 64 + bi * 32 +
                              (rg & 3) + 8 * (rg >> 2) + 4 * hh;
                    ofp[(size_t)row * 512 + col] = fmaxf(acc[bi][bj][rg] + bv, 0.f);
                }
        }
    }
}

// ---- flash attention block (R4 code verbatim, 512 threads, 128q/8-wave) ----
__device__ __forceinline__ void attn_block(
    const int qt, const int h, const int b, unsigned char* sm,
    const f16* __restrict__ Q, const f16* __restrict__ K,
    const u16* __restrict__ VT, const int* __restrict__ G,
    f16* __restrict__ Y) {
    u16 (*Ks)[4096] = (u16(*)[4096])sm;            // 16 KB
    u16 (*Vs)[4096] = (u16(*)[4096])(sm + 16384);  // 16 KB
    int* bnd = (int*)(sm + 32768);                 // 9 ints

    const int q0 = qt * 128;
    const int tid = threadIdx.x;
    const int w = tid >> 6, lane = tid & 63;
    const int ln = lane & 15, quad = lane >> 4;

    const f16* Qb = Q + (size_t)b * Ssz * Dsz;
    const f16* Kb = K + (size_t)b * Ssz * Dsz;
    const u16* Vtb = VT + (size_t)(b * Hn + h) * 32 * 4096;
    const int* Gb = G + (size_t)b * Ssz;

    // group boundary table (sorted groups): bnd[g] = first i with G[i] >= g
    if (tid < 9) bnd[tid] = Ssz;
    __syncthreads();
    {
        int i0 = tid * 4;                      // 512 threads x 4 = 2048
        int4 gi = *(const int4*)(Gb + i0);
        int gp = (i0 == 0) ? -1 : Gb[i0 - 1];
        int ga[5] = {gp, gi.x, gi.y, gi.z, gi.w};
#pragma unroll
        for (int j = 0; j < 4; j++)
            for (int g = ga[j] + 1; g <= ga[j + 1]; g++) bnd[g] = i0 + j;
    }

    // Q B-frags for 16x16x32 (n=ln, k=quad*8+j), hoisted
    f16x8 qf[2];
    {
        const f16* qrow = Qb + (size_t)(q0 + w * 16 + ln) * Dsz + h * 64;
        qf[0] = *(const f16x8*)(qrow + quad * 8);
        qf[1] = *(const f16x8*)(qrow + 32 + quad * 8);
    }
    const int gq = Gb[q0 + w * 16 + ln];
    const int gqmin = Gb[q0], gqmax = Gb[q0 + 127];

    // visited tile range (sorted groups => contiguous)
    int gf = 0, gl = 0; bool ov = false;
    if (lane < 32) {
        gf = Gb[lane * 64]; gl = Gb[lane * 64 + 63];
        ov = (gl >= gqmin) && (gf <= gqmax);
    }
    unsigned long long mask = __ballot(ov);
    const int kt_lo = __builtin_ctzll(mask);
    const int kt_hi = 63 - __builtin_clzll(mask);

    __syncthreads();                         // bnd ready
    const int sq = bnd[gq];
    const unsigned usz = (unsigned)(bnd[gq + 1] - sq);

    f32x4 o[4];
    const f32x4 z4 = {0.f, 0.f, 0.f, 0.f};
#pragma unroll
    for (int nd = 0; nd < 4; nd++) o[nd] = z4;
    float lsum = 0.f;

#define STAGE_K(kt, bi_)                                                       \
    {                                                                          \
        const f16* Ktile = Kb + (size_t)(kt) * 64 * Dsz + h * 64;              \
        int row = tid >> 3, c = tid & 7;                                       \
        gl2lds16(Ktile + (size_t)row * Dsz + ((c ^ (row & 7)) << 3),           \
                 Ks[bi_] + tid * 8);                                           \
    }
#define STAGE_V(kt, bi_)                                                       \
    {                                                                          \
        const u16* Vtile = Vtb + (size_t)(kt) * 4096;                          \
        int row = tid >> 3, c = tid & 7;                                       \
        gl2lds16(Vtile + row * 64 + ((c ^ (row & 7)) << 3),                    \
                 Vs[bi_] + tid * 8);                                           \
    }

    STAGE_K(kt_lo, 0)
    STAGE_V(kt_lo, 0)

    int buf = 0;
    for (int kt = kt_lo; kt <= kt_hi; kt++) {
        __syncthreads();                 // buf ready; all waves off buf^1
        if (kt < kt_hi) { STAGE_K(kt + 1, buf ^ 1) STAGE_V(kt + 1, buf ^ 1) }
        const u16* ks = Ks[buf];
        const u16* vs = Vs[buf];
        const int k0 = kt * 64;

        f16x4 pf[4];
#pragma unroll
        for (int kb = 0; kb < 4; kb++) {
            f32x4 s = z4;
#pragma unroll
            for (int kk = 0; kk < 2; kk++) {   // S^T = K Q^T, K=32 per mfma
                int key = kb * 16 + ln;
                int ch = key * 8 + ((kk * 4 + quad) ^ (key & 7));
                f16x8 kf = *(const f16x8*)(ks + ch * 8);
                s = __builtin_amdgcn_mfma_f32_16x16x32_f16(kf, qf[kk], s, 0, 0, 0);
            }
            const int ckb = k0 + kb * 16 + quad * 4;
            f16x4 pp;
#pragma unroll
            for (int r = 0; r < 4; r++) {
                float t = s[r] - 4.0f;       // Q pre-scaled; fixed-shift softmax
                float sval = ((unsigned)(ckb + r - sq) < usz) ? t : -1e9f;
                float e = __expf(sval);
                lsum += e;
                pp[r] = (f16)e;
            }
            pf[kb] = pp;
        }
        // O += P V
#pragma unroll
        for (int nd = 0; nd < 4; nd++)
#pragma unroll
            for (int kc = 0; kc < 4; kc++) {
                int addr = (((nd * 16 + ln) * 8 +
                             ((kc * 2 + (quad >> 1)) ^ (ln & 7))) << 3) +
                           (quad & 1) * 4;
                f16x4 vf = *(const f16x4*)(vs + addr);
                o[nd] = __builtin_amdgcn_mfma_f32_16x16x16f16(pf[kc], vf, o[nd], 0, 0, 0);
            }
        buf ^= 1;
    }

    lsum += __shfl_xor(lsum, 16);
    lsum += __shfl_xor(lsum, 32);
    float linv = 1.0f / lsum;
#pragma unroll
    for (int r = 0; r < 4; r++) {
        float lr = __shfl(linv, (lane & 48) | (quad * 4 + r));
        size_t row = (size_t)b * Ssz + q0 + w * 16 + quad * 4 + r;
#pragma unroll
        for (int nd = 0; nd < 4; nd++)
            Y[row * Dsz + h * 64 + nd * 16 + ln] = (f16)(o[nd][r] * lr);
    }
#undef STAGE_K
#undef STAGE_V
}

// ============================================================================
// R5 MEGAKERNEL: all 4 stages in ONE persistent launch + 3 grid barriers.
// Co-residency by construction: 512 blocks x 512 thr, 64KB LDS -> 2 blocks/CU,
// __launch_bounds__(512,4) caps VGPR<=128 -> 2 blocks/CU -> all 512 resident.
// Stage math byte-identical to R4. Predicted dur 130-138us (R4: 147.1;
// removes ~3 dispatch gaps ~20us, spends ~4-6us on barriers).
// ============================================================================
__global__ __launch_bounds__(512, 4) void mega(
    const float* __restrict__ x, const int* __restrict__ gids,
    const float* __restrict__ Wq, const float* __restrict__ bq,
    const float* __restrict__ Wk, const float* __restrict__ bk,
    const float* __restrict__ Wv, const float* __restrict__ bv,
    const float* __restrict__ Wo, const float* __restrict__ bo,
    float* __restrict__ out,
    f16* xb, f16* qb, f16* kb2, u16* vtb, f16* yb,
    f16* Wtqkv, f16* Wto) {
    __shared__ __align__(16) unsigned char sm[65536];
    const int blk = blockIdx.x;
    const int tid = threadIdx.x;

    // ---- stage 0: prep (x fp32->fp16; weight transpose on blocks 0-255) ----
    {
        const float4* xv = (const float4*)x;
#pragma unroll
        for (int r = 0; r < 2; r++) {
            int i = blk * 512 + tid + r * (NBLK * 512);
            float4 a = xv[2 * i], b = xv[2 * i + 1];
            f16x8 o;
            o[0] = (f16)a.x; o[1] = (f16)a.y; o[2] = (f16)a.z; o[3] = (f16)a.w;
            o[4] = (f16)b.x; o[5] = (f16)b.y; o[6] = (f16)b.z; o[7] = (f16)b.w;
            ((f16x8*)xb)[i] = o;
        }
        if (blk < 256) {
            float (*T)[65] = (float(*)[65])sm;   // 16.6 KB
            const int z = blk >> 6;
            const int n0 = (blk & 7) * 64, k0 = ((blk >> 3) & 7) * 64;
            const float* W = (z == 0) ? Wq : (z == 1) ? Wk : (z == 2) ? Wv : Wo;
#pragma unroll
            for (int i = 0; i < 8; i++) {
                int e = tid + i * 512;
                int r = e >> 6, c = e & 63;
                T[r][c] = W[(size_t)(k0 + r) * Dsz + n0 + c];
            }
            __syncthreads();
            f16* dst = (z < 3) ? (Wtqkv + ((size_t)z * 512 + n0) * Dsz + k0)
                               : (Wto + (size_t)n0 * Dsz + k0);
#pragma unroll
            for (int i = 0; i < 8; i++) {
                int e = tid + i * 512;
                int r = e >> 6, c = e & 63;
                dst[(size_t)r * Dsz + c] = (f16)(T[c][r]);
            }
        }
    }
    grid_barrier();

    // ---- stage 1: QKV GEMM — 768 virtual 256-thr tiles as 384 lockstep pairs
    if (blk < 384) {
        const int hw = tid >> 8, htid = tid & 255;
        const int vcol = blk % 12, rb = (blk / 12) * 2 + hw;   // same colg pair
        gemm_tile<0>(htid, vcol, rb, (u16*)(sm + hw * 32768),
                     xb, Wtqkv, qb, kb2, vtb, bq, bk, bv, nullptr, nullptr);
    }
    grid_barrier();

    // ---- stage 2: attention — 512 virtual blocks 1:1 ----
    attn_block(blk & 15, (blk >> 4) & 7, blk >> 7, sm, qb, kb2, vtb, gids, yb);
    grid_barrier();

    // ---- stage 3: out projection — 256 virtual tiles, lower half active ----
    if (blk < 256) {
        const int hw = tid >> 8, htid = tid & 255;
        if (hw == 0) {
            gemm_tile<1>(htid, blk % 4, blk / 4, (u16*)sm,
                         yb, Wto, nullptr, nullptr, nullptr,
                         nullptr, nullptr, nullptr, out, bo);
        } else {
            // sync-matched idle: 2 barriers per K-step x 8 (MODE1 epilogue: 0)
            for (int k0 = 0; k0 < 512; k0 += 64) { __syncthreads(); __syncthreads(); }
        }
    }
}

extern "C" void kernel_launch(void* const* d_in, const int* in_sizes, int n_in,
                              void* d_out, int out_size, void* d_ws, size_t ws_size,
                              hipStream_t stream) {
    const float* x  = (const float*)d_in[0];
    const int*   g  = (const int*)d_in[1];
    const float* Wq = (const float*)d_in[2];
    const float* bq = (const float*)d_in[3];
    const float* Wk = (const float*)d_in[4];
    const float* bk = (const float*)d_in[5];
    const float* Wv = (const float*)d_in[6];
    const float* bv = (const float*)d_in[7];
    const float* Wo = (const float*)d_in[8];
    const float* bo = (const float*)d_in[9];
    float* out = (float*)d_out;

    const size_t E = (size_t)Bsz * Ssz * Dsz;   // 4M elements
    f16* xb  = (f16*)d_ws;
    f16* qb  = xb + E;                  // [B,S,D] fp16 (Q pre-scaled 0.125)
    f16* kb2 = qb + E;                  // [B,S,D] fp16
    u16* vtb = (u16*)(kb2 + E);         // packed V^T [bh][t][64][64]
    f16* yb  = (f16*)(vtb + E);         // [B,S,D] fp16
    f16* Wtqkv = yb + E;                // [1536][512]
    f16* Wto   = Wtqkv + 1536 * 512;    // [512][512]

    mega<<<NBLK, 512, 0, stream>>>(x, g, Wq, bq, Wk, bk, Wv, bv, Wo, bo,
                                   out, xb, qb, kb2, vtb, yb, Wtqkv, Wto);
}

// Round 6
// 203.438 us; speedup vs baseline: 2.3323x; 2.3323x over previous
//
#include <hip/hip_runtime.h>
#include <cmath>

#define Bsz 4
#define Ssz 2048
#define Dsz 512
#define Hn 8

typedef unsigned short u16;
typedef _Float16 f16;
typedef __attribute__((ext_vector_type(4))) _Float16 f16x4;
typedef __attribute__((ext_vector_type(8))) _Float16 f16x8;
typedef __attribute__((ext_vector_type(8))) unsigned short us8;
typedef __attribute__((ext_vector_type(4))) float f32x4;
typedef __attribute__((ext_vector_type(16))) float f32x16;

__device__ __forceinline__ void gl2lds16(const void* g, void* l) {
    __builtin_amdgcn_global_load_lds(
        (const __attribute__((address_space(1))) void*)g,
        (__attribute__((address_space(3))) void*)l, 16, 0, 0);
}

// ---- fused prep: blocks [0,2048) convert x (fp32->fp16, 8/thread);
//      blocks [2048,2304) transpose+convert the 4 weight matrices.
//      Block 0 also zeroes the 64 finisher counters (agent-scope atomic
//      stores -> visible to attn's atomicAdds; re-done every launch since
//      the harness re-poisons the workspace).
__global__ __launch_bounds__(256) void prep(const float* __restrict__ x,
                                            f16* __restrict__ xb,
                                            const float* __restrict__ Wq,
                                            const float* __restrict__ Wk,
                                            const float* __restrict__ Wv,
                                            const float* __restrict__ Wo,
                                            f16* __restrict__ Wtqkv,
                                            f16* __restrict__ Wto,
                                            int* __restrict__ cnt) {
    const int blk = blockIdx.x;
    const int tid = threadIdx.x;
    if (blk < 2048) {
        if (blk == 0 && tid < 64)
            __hip_atomic_store(&cnt[tid], 0, __ATOMIC_RELAXED,
                               __HIP_MEMORY_SCOPE_AGENT);
        int i = blk * 256 + tid;
        const float4* xv = (const float4*)x;
        float4 a = xv[2 * i], b = xv[2 * i + 1];
        f16x8 o;
        o[0] = (f16)a.x; o[1] = (f16)a.y; o[2] = (f16)a.z; o[3] = (f16)a.w;
        o[4] = (f16)b.x; o[5] = (f16)b.y; o[6] = (f16)b.z; o[7] = (f16)b.w;
        ((f16x8*)xb)[i] = o;
        return;
    }
    __shared__ float T[64][65];
    const int bz = blk - 2048;             // 256 blocks: 8 x 8 x 4
    const int z = bz >> 6;
    const int n0 = (bz & 7) * 64, k0 = ((bz >> 3) & 7) * 64;
    const float* W = (z == 0) ? Wq : (z == 1) ? Wk : (z == 2) ? Wv : Wo;
#pragma unroll
    for (int i = 0; i < 16; i++) {
        int e = tid + i * 256;
        int r = e >> 6, c = e & 63;
        T[r][c] = W[(size_t)(k0 + r) * Dsz + n0 + c];
    }
    __syncthreads();
    f16* dst = (z < 3) ? (Wtqkv + ((size_t)z * 512 + n0) * Dsz + k0)
                       : (Wto + (size_t)n0 * Dsz + k0);
#pragma unroll
    for (int i = 0; i < 16; i++) {
        int e = tid + i * 256;
        int r = e >> 6, c = e & 63;
        dst[(size_t)r * Dsz + c] = (f16)(T[c][r]);
    }
}

// ---- 128x128-tile fp16 MFMA GEMM (32x32x16), C = relu(A @ Bt^T + bias) ----
// MODE 0 only (QKV): Q (x0.125, exact pow2) / K row-major f16; V -> packed
// V^T tiles [bh][t][64 d][64 s].
template <int MODE>
__global__ __launch_bounds__(256) void gemm128(
    const f16* __restrict__ A, const f16* __restrict__ Bt,
    f16* o0, f16* o1, u16* o2v,
    const float* b0, const float* b1, const float* b2,
    float* ofp, const float* bias_f) {
    __shared__ __align__(16) u16 smem[2 * 128 * 64];   // As | Bs ; reused as T
    u16* As = smem;
    u16* Bs = smem + 128 * 64;
    const int tid = threadIdx.x;
    const int colg0 = blockIdx.x * 128;
    const int row0 = blockIdx.y * 128;
    const int w = tid >> 6, lane = tid & 63;
    const int nn = lane & 31, hh = lane >> 5;
    const int wr = w >> 1, wc = w & 1;

    f32x16 acc[2][2];
#pragma unroll
    for (int bi = 0; bi < 2; bi++)
#pragma unroll
        for (int bj = 0; bj < 2; bj++)
#pragma unroll
            for (int e = 0; e < 16; e++) acc[bi][bj][e] = 0.f;

    const f16* Ablk = A + (size_t)row0 * 512;
    const f16* Bblk = Bt + (size_t)colg0 * 512;

    for (int k0 = 0; k0 < 512; k0 += 64) {
        __syncthreads();
#pragma unroll
        for (int i = 0; i < 4; i++) {
            int p = tid + i * 256;           // 16B chunk id
            int m = p >> 3, kc = p & 7;
            int gk = ((kc ^ (m & 7)) << 3);  // XOR-swizzled k origin
            gl2lds16(Ablk + (size_t)m * 512 + k0 + gk, As + p * 8);
            gl2lds16(Bblk + (size_t)m * 512 + k0 + gk, Bs + p * 8);
        }
        __syncthreads();
#pragma unroll
        for (int t = 0; t < 4; t++) {        // four 32x32x16 k-steps
            f16x8 af[2], bfr[2];
#pragma unroll
            for (int bi = 0; bi < 2; bi++) {
                int r = wr * 64 + bi * 32 + nn;
                int ch = r * 8 + ((t * 2 + hh) ^ (r & 7));
                af[bi] = *(const f16x8*)(As + ch * 8);
            }
#pragma unroll
            for (int bj = 0; bj < 2; bj++) {
                int n = wc * 64 + bj * 32 + nn;
                int ch = n * 8 + ((t * 2 + hh) ^ (n & 7));
                bfr[bj] = *(const f16x8*)(Bs + ch * 8);
            }
#pragma unroll
            for (int bi = 0; bi < 2; bi++)
#pragma unroll
                for (int bj = 0; bj < 2; bj++)
                    acc[bi][bj] = __builtin_amdgcn_mfma_f32_32x32x16_f16(
                        af[bi], bfr[bj], acc[bi][bj], 0, 0, 0);
        }
    }

    // C/D mapping (m74/m101): col = nn, rowoff = (reg&3) + 8*(reg>>2) + 4*hh
    if (MODE == 0) {
        const int sel = colg0 >> 9;
        const int c0 = colg0 & 511;
        if (sel < 2) {                      // Q or K: plain row-major
            f16* outp = (sel == 0) ? o0 : o1;
            const float* bp = (sel == 0) ? b0 : b1;
            const float sc = (sel == 0) ? 0.125f : 1.0f;
#pragma unroll
            for (int bj = 0; bj < 2; bj++) {
                int col = c0 + wc * 64 + bj * 32 + nn;
                float bv = bp[col];
#pragma unroll
                for (int bi = 0; bi < 2; bi++)
#pragma unroll
                    for (int rg = 0; rg < 16; rg++) {
                        int row = row0 + wr * 64 + bi * 32 +
                                  (rg & 3) + 8 * (rg >> 2) + 4 * hh;
                        outp[(size_t)row * 512 + col] =
                            (f16)(fmaxf(acc[bi][bj][rg] + bv, 0.f) * sc);
                    }
            }
        } else {                            // V: LDS transpose -> packed V^T tiles
            const int hh_head = c0 >> 6;
            f16 (*T)[136] = (f16(*)[136])smem;   // 64 x 136 fp16
            const int bb = row0 >> 11;
            const int t0 = (row0 & 2047) >> 6;
            __syncthreads();                // all waves done reading As/Bs
#pragma unroll
            for (int ph = 0; ph < 2; ph++) {
                if (wc == ph) {
#pragma unroll
                    for (int bj = 0; bj < 2; bj++) {
                        int d = bj * 32 + nn;
                        float bv = b2[c0 + ph * 64 + d];
#pragma unroll
                        for (int bi = 0; bi < 2; bi++)
#pragma unroll
                            for (int rg = 0; rg < 16; rg++) {
                                int s = wr * 64 + bi * 32 +
                                        (rg & 3) + 8 * (rg >> 2) + 4 * hh;
                                T[d][s] = (f16)fmaxf(acc[bi][bj][rg] + bv, 0.f);
                            }
                    }
                }
                __syncthreads();
#pragma unroll
                for (int ii = 0; ii < 4; ii++) {
                    int oct = tid + ii * 256;        // 1024 octets = 2 tiles
                    int tt = oct >> 9, rem = oct & 511;
                    int d = rem >> 3, s8 = rem & 7;
                    us8 val = *(const us8*)(&T[d][tt * 64 + s8 * 8]);
                    size_t dst = (((size_t)((bb * 8 + hh_head + ph) * 32 + t0 + tt)) << 12)
                                 + d * 64 + s8 * 8;
                    *(us8*)(o2v + dst) = val;
                }
                __syncthreads();
            }
        }
    } else {
#pragma unroll
        for (int bj = 0; bj < 2; bj++) {
            int col = colg0 + wc * 64 + bj * 32 + nn;
            float bv = bias_f[col];
#pragma unroll
            for (int bi = 0; bi < 2; bi++)
#pragma unroll
                for (int rg = 0; rg < 16; rg++) {
                    int row = row0 + wr * 64 + bi * 32 +
                              (rg & 3) + 8 * (rg >> 2) + 4 * hh;
                    ofp[(size_t)row * 512 + col] = fmaxf(acc[bi][bj][rg] + bv, 0.f);
                }
        }
    }
}

// ---- flash attention (R4 structure) + 8th-finisher out-projection ----
// Per (b,qt) there are 8 attn blocks (one per head). After its Y-store each
// block does: release fence + atomicAdd(cnt[b*16+qt]). The 8th arrival
// (old==7) acquire-fences and computes out rows [rb*128, rb*128+128) x 512
// itself (512-thread 128x128 gemm, identical MFMA K-order as gemm128<1> ->
// bit-identical output). No spins, no grid barrier; overlaps attn tail.
__global__ __launch_bounds__(512, 4) void attn_mfma(
    const f16* __restrict__ Q, const f16* __restrict__ K,
    const u16* __restrict__ VT, const int* __restrict__ G,
    f16* __restrict__ Y,
    const f16* __restrict__ Wto, const float* __restrict__ bo,
    float* __restrict__ out, int* __restrict__ cnt) {
    __shared__ __align__(16) u16 sm[16384];   // 32KB: Ks(2x4096)|Vs(2x4096); reused As|Bs
    __shared__ int bnd[9];
    __shared__ int finflag;
    u16* Ksb = sm;
    u16* Vsb = sm + 8192;

    const int qt = blockIdx.x, h = blockIdx.y, b = blockIdx.z;
    const int q0 = qt * 128;
    const int tid = threadIdx.x;
    const int w = tid >> 6, lane = tid & 63;
    const int ln = lane & 15, quad = lane >> 4;

    const f16* Qb = Q + (size_t)b * Ssz * Dsz;
    const f16* Kb = K + (size_t)b * Ssz * Dsz;
    const u16* Vtb = VT + (size_t)(b * Hn + h) * 32 * 4096;
    const int* Gb = G + (size_t)b * Ssz;

    // group boundary table (sorted groups): bnd[g] = first i with G[i] >= g
    if (tid < 9) bnd[tid] = Ssz;
    __syncthreads();
    {
        int i0 = tid * 4;                      // 512 threads x 4 = 2048
        int4 gi = *(const int4*)(Gb + i0);
        int gp = (i0 == 0) ? -1 : Gb[i0 - 1];
        int ga[5] = {gp, gi.x, gi.y, gi.z, gi.w};
#pragma unroll
        for (int j = 0; j < 4; j++)
            for (int g = ga[j] + 1; g <= ga[j + 1]; g++) bnd[g] = i0 + j;
    }

    // Q B-frags for 16x16x32 (n=ln, k=quad*8+j), hoisted
    f16x8 qf[2];
    {
        const f16* qrow = Qb + (size_t)(q0 + w * 16 + ln) * Dsz + h * 64;
        qf[0] = *(const f16x8*)(qrow + quad * 8);
        qf[1] = *(const f16x8*)(qrow + 32 + quad * 8);
    }
    const int gq = Gb[q0 + w * 16 + ln];
    const int gqmin = Gb[q0], gqmax = Gb[q0 + 127];

    // visited tile range (sorted groups => contiguous)
    int gf = 0, gl = 0; bool ov = false;
    if (lane < 32) {
        gf = Gb[lane * 64]; gl = Gb[lane * 64 + 63];
        ov = (gl >= gqmin) && (gf <= gqmax);
    }
    unsigned long long mask = __ballot(ov);
    const int kt_lo = __builtin_ctzll(mask);
    const int kt_hi = 63 - __builtin_clzll(mask);

    __syncthreads();                         // bnd ready
    const int sq = bnd[gq];
    const unsigned usz = (unsigned)(bnd[gq + 1] - sq);

    f32x4 o[4];
    const f32x4 z4 = {0.f, 0.f, 0.f, 0.f};
#pragma unroll
    for (int nd = 0; nd < 4; nd++) o[nd] = z4;
    float lsum = 0.f;

#define STAGE_K(kt, bi_)                                                       \
    {                                                                          \
        const f16* Ktile = Kb + (size_t)(kt) * 64 * Dsz + h * 64;              \
        int row = tid >> 3, c = tid & 7;                                       \
        gl2lds16(Ktile + (size_t)row * Dsz + ((c ^ (row & 7)) << 3),           \
                 Ksb + (bi_) * 4096 + tid * 8);                                \
    }
#define STAGE_V(kt, bi_)                                                       \
    {                                                                          \
        const u16* Vtile = Vtb + (size_t)(kt) * 4096;                          \
        int row = tid >> 3, c = tid & 7;                                       \
        gl2lds16(Vtile + row * 64 + ((c ^ (row & 7)) << 3),                    \
                 Vsb + (bi_) * 4096 + tid * 8);                                \
    }

    STAGE_K(kt_lo, 0)
    STAGE_V(kt_lo, 0)

    int buf = 0;
    for (int kt = kt_lo; kt <= kt_hi; kt++) {
        __syncthreads();                 // buf ready; all waves off buf^1
        if (kt < kt_hi) { STAGE_K(kt + 1, buf ^ 1) STAGE_V(kt + 1, buf ^ 1) }
        const u16* ks = Ksb + buf * 4096;
        const u16* vs = Vsb + buf * 4096;
        const int k0 = kt * 64;

        f16x4 pf[4];
#pragma unroll
        for (int kb = 0; kb < 4; kb++) {
            f32x4 s = z4;
#pragma unroll
            for (int kk = 0; kk < 2; kk++) {   // S^T = K Q^T, K=32 per mfma
                int key = kb * 16 + ln;
                int ch = key * 8 + ((kk * 4 + quad) ^ (key & 7));
                f16x8 kf = *(const f16x8*)(ks + ch * 8);
                s = __builtin_amdgcn_mfma_f32_16x16x32_f16(kf, qf[kk], s, 0, 0, 0);
            }
            const int ckb = k0 + kb * 16 + quad * 4;
            f16x4 pp;
#pragma unroll
            for (int r = 0; r < 4; r++) {
                float t = s[r] - 4.0f;       // Q pre-scaled; fixed-shift softmax
                float sval = ((unsigned)(ckb + r - sq) < usz) ? t : -1e9f;
                float e = __expf(sval);
                lsum += e;
                pp[r] = (f16)e;
            }
            pf[kb] = pp;
        }
        // O += P V
#pragma unroll
        for (int nd = 0; nd < 4; nd++)
#pragma unroll
            for (int kc = 0; kc < 4; kc++) {
                int addr = (((nd * 16 + ln) * 8 +
                             ((kc * 2 + (quad >> 1)) ^ (ln & 7))) << 3) +
                           (quad & 1) * 4;
                f16x4 vf = *(const f16x4*)(vs + addr);
                o[nd] = __builtin_amdgcn_mfma_f32_16x16x16f16(pf[kc], vf, o[nd], 0, 0, 0);
            }
        buf ^= 1;
    }

    lsum += __shfl_xor(lsum, 16);
    lsum += __shfl_xor(lsum, 32);
    float linv = 1.0f / lsum;
#pragma unroll
    for (int r = 0; r < 4; r++) {
        float lr = __shfl(linv, (lane & 48) | (quad * 4 + r));
        size_t row = (size_t)b * Ssz + q0 + w * 16 + quad * 4 + r;
#pragma unroll
        for (int nd = 0; nd < 4; nd++)
            Y[row * Dsz + h * 64 + nd * 16 + ln] = (f16)(o[nd][r] * lr);
    }
#undef STAGE_K
#undef STAGE_V

    // ---- 8th-finisher gate ----
    __syncthreads();                  // all waves' Y stores drained (vmcnt 0)
    const int rb = b * 16 + qt;
    if (tid == 0) {
        __threadfence();              // release: wbl2 -> publish this block's Y
        int old = __hip_atomic_fetch_add(&cnt[rb], 1, __ATOMIC_ACQ_REL,
                                         __HIP_MEMORY_SCOPE_AGENT);
        finflag = (old == 7);
        if (old == 7) __threadfence();   // acquire: inv -> see 7 peers' Y
    }
    __syncthreads();
    if (!finflag) return;

    // ---- out projection for rows [rb*128, rb*128+128), cols 0..511 ----
    // 512-thread 128x128 tile: wave grid 2(row) x 4(col), per wave 64x32 out.
    {
        u16* As = sm;                 // 128 rows x 8 chunks (16KB)
        u16* Bs = sm + 8192;          // 128 cols x 8 chunks (16KB)
        const int nn = lane & 31, hh = lane >> 5;
        const int wr = w >> 2, wc = w & 3;
        const f16* Ablk = Y + (size_t)(rb * 128) * 512;

        for (int vcol = 0; vcol < 4; vcol++) {
            const f16* Bblk = Wto + (size_t)(vcol * 128) * 512;
            f32x16 acc[2];
#pragma unroll
            for (int e = 0; e < 16; e++) { acc[0][e] = 0.f; acc[1][e] = 0.f; }

            for (int k0 = 0; k0 < 512; k0 += 64) {
                __syncthreads();
#pragma unroll
                for (int i = 0; i < 2; i++) {
                    int p = tid + i * 512;       // 1024 chunks each for A,B
                    int m = p >> 3, kc = p & 7;
                    int gk = ((kc ^ (m & 7)) << 3);
                    gl2lds16(Ablk + (size_t)m * 512 + k0 + gk, As + p * 8);
                    gl2lds16(Bblk + (size_t)m * 512 + k0 + gk, Bs + p * 8);
                }
                __syncthreads();
#pragma unroll
                for (int t = 0; t < 4; t++) {
                    f16x8 af[2], bfr;
#pragma unroll
                    for (int bi = 0; bi < 2; bi++) {
                        int r = wr * 64 + bi * 32 + nn;
                        int ch = r * 8 + ((t * 2 + hh) ^ (r & 7));
                        af[bi] = *(const f16x8*)(As + ch * 8);
                    }
                    {
                        int n = wc * 32 + nn;
                        int ch = n * 8 + ((t * 2 + hh) ^ (n & 7));
                        bfr = *(const f16x8*)(Bs + ch * 8);
                    }
                    acc[0] = __builtin_amdgcn_mfma_f32_32x32x16_f16(
                        af[0], bfr, acc[0], 0, 0, 0);
                    acc[1] = __builtin_amdgcn_mfma_f32_32x32x16_f16(
                        af[1], bfr, acc[1], 0, 0, 0);
                }
            }
            int col = vcol * 128 + wc * 32 + nn;
            float bv = bo[col];
#pragma unroll
            for (int bi = 0; bi < 2; bi++)
#pragma unroll
                for (int rg = 0; rg < 16; rg++) {
                    int row = rb * 128 + wr * 64 + bi * 32 +
                              (rg & 3) + 8 * (rg >> 2) + 4 * hh;
                    out[(size_t)row * 512 + col] = fmaxf(acc[bi][rg] + bv, 0.f);
                }
        }
    }
}

// ============================================================================
// R6: revert megakernel (R5: acquire-SPIN = buffer_inv storm, 380us idle).
// R4 pipeline + 8th-finisher fusion of out-projection into attn (spin-free:
// 1 release fence + 1 atomicAdd per block; 8th arrival computes the tile).
// 3 dispatches. Predicted dur 136-142us (R4 147.07 - gemm1 4.4 - gap ~8
// + fence ~2). Ledger: fills ~80us fixed, prep ~2, gemm0 ~11, attn ~21+5.
// ============================================================================
extern "C" void kernel_launch(void* const* d_in, const int* in_sizes, int n_in,
                              void* d_out, int out_size, void* d_ws, size_t ws_size,
                              hipStream_t stream) {
    const float* x  = (const float*)d_in[0];
    const int*   g  = (const int*)d_in[1];
    const float* Wq = (const float*)d_in[2];
    const float* bq = (const float*)d_in[3];
    const float* Wk = (const float*)d_in[4];
    const float* bk = (const float*)d_in[5];
    const float* Wv = (const float*)d_in[6];
    const float* bv = (const float*)d_in[7];
    const float* Wo = (const float*)d_in[8];
    const float* bo = (const float*)d_in[9];
    float* out = (float*)d_out;

    const size_t E = (size_t)Bsz * Ssz * Dsz;   // 4M elements
    f16* xb  = (f16*)d_ws;
    f16* qb  = xb + E;                  // [B,S,D] fp16 (Q pre-scaled 0.125)
    f16* kb2 = qb + E;                  // [B,S,D] fp16
    u16* vtb = (u16*)(kb2 + E);         // packed V^T [bh][t][64][64]
    f16* yb  = (f16*)(vtb + E);         // [B,S,D] fp16
    f16* Wtqkv = yb + E;                // [1536][512]
    f16* Wto   = Wtqkv + 1536 * 512;    // [512][512]
    int* cnt   = (int*)(Wto + 512 * 512);   // 64 finisher counters

    prep<<<2304, 256, 0, stream>>>(x, xb, Wq, Wk, Wv, Wo, Wtqkv, Wto, cnt);
    gemm128<0><<<dim3(12, 64), 256, 0, stream>>>(xb, Wtqkv, qb, kb2, vtb,
                                                 bq, bk, bv, nullptr, nullptr);
    attn_mfma<<<dim3(Ssz / 128, Hn, Bsz), 512, 0, stream>>>(
        qb, kb2, vtb, g, yb, Wto, bo, out, cnt);
}

// Round 7
// 145.344 us; speedup vs baseline: 3.2646x; 1.3997x over previous
//
#include <hip/hip_runtime.h>
#include <cmath>

#define Bsz 4
#define Ssz 2048
#define Dsz 512
#define Hn 8

typedef unsigned short u16;
typedef _Float16 f16;
typedef __attribute__((ext_vector_type(4))) _Float16 f16x4;
typedef __attribute__((ext_vector_type(8))) _Float16 f16x8;
typedef __attribute__((ext_vector_type(8))) unsigned short us8;
typedef __attribute__((ext_vector_type(4))) float f32x4;
typedef __attribute__((ext_vector_type(16))) float f32x16;

__device__ __forceinline__ void gl2lds16(const void* g, void* l) {
    __builtin_amdgcn_global_load_lds(
        (const __attribute__((address_space(1))) void*)g,
        (__attribute__((address_space(3))) void*)l, 16, 0, 0);
}

// ---- fused prep: blocks [0,2048) convert x (fp32->fp16, 8/thread);
//      blocks [2048,2304) transpose+convert the 4 weight matrices ----
__global__ __launch_bounds__(256) void prep(const float* __restrict__ x,
                                            f16* __restrict__ xb,
                                            const float* __restrict__ Wq,
                                            const float* __restrict__ Wk,
                                            const float* __restrict__ Wv,
                                            const float* __restrict__ Wo,
                                            f16* __restrict__ Wtqkv,
                                            f16* __restrict__ Wto) {
    const int blk = blockIdx.x;
    const int tid = threadIdx.x;
    if (blk < 2048) {
        int i = blk * 256 + tid;
        const float4* xv = (const float4*)x;
        float4 a = xv[2 * i], b = xv[2 * i + 1];
        f16x8 o;
        o[0] = (f16)a.x; o[1] = (f16)a.y; o[2] = (f16)a.z; o[3] = (f16)a.w;
        o[4] = (f16)b.x; o[5] = (f16)b.y; o[6] = (f16)b.z; o[7] = (f16)b.w;
        ((f16x8*)xb)[i] = o;
        return;
    }
    __shared__ float T[64][65];
    const int bz = blk - 2048;             // 256 blocks: 8 x 8 x 4
    const int z = bz >> 6;
    const int n0 = (bz & 7) * 64, k0 = ((bz >> 3) & 7) * 64;
    const float* W = (z == 0) ? Wq : (z == 1) ? Wk : (z == 2) ? Wv : Wo;
#pragma unroll
    for (int i = 0; i < 16; i++) {
        int e = tid + i * 256;
        int r = e >> 6, c = e & 63;
        T[r][c] = W[(size_t)(k0 + r) * Dsz + n0 + c];
    }
    __syncthreads();
    f16* dst = (z < 3) ? (Wtqkv + ((size_t)z * 512 + n0) * Dsz + k0)
                       : (Wto + (size_t)n0 * Dsz + k0);
#pragma unroll
    for (int i = 0; i < 16; i++) {
        int e = tid + i * 256;
        int r = e >> 6, c = e & 63;
        dst[(size_t)r * Dsz + c] = (f16)(T[c][r]);
    }
}

// ---- 128x128-tile fp16 MFMA GEMM (32x32x16), C = relu(A @ Bt^T + bias) ----
// MODE 0: Q (x0.125, exact pow2 -> bit-identical attn), K plain,
//         V -> LDS-transposed packed V^T [bh][t][64 d][64 s]. MODE 1: fp32 out.
template <int MODE>
__global__ __launch_bounds__(256) void gemm128(
    const f16* __restrict__ A, const f16* __restrict__ Bt,
    f16* o0, f16* o1, u16* o2v,
    const float* b0, const float* b1, const float* b2,
    float* ofp, const float* bias_f) {
    __shared__ __align__(16) u16 smem[2 * 128 * 64];   // As | Bs ; reused as T
    u16* As = smem;
    u16* Bs = smem + 128 * 64;
    const int tid = threadIdx.x;
    const int colg0 = blockIdx.x * 128;
    const int row0 = blockIdx.y * 128;
    const int w = tid >> 6, lane = tid & 63;
    const int nn = lane & 31, hh = lane >> 5;
    const int wr = w >> 1, wc = w & 1;

    f32x16 acc[2][2];
#pragma unroll
    for (int bi = 0; bi < 2; bi++)
#pragma unroll
        for (int bj = 0; bj < 2; bj++)
#pragma unroll
            for (int e = 0; e < 16; e++) acc[bi][bj][e] = 0.f;

    const f16* Ablk = A + (size_t)row0 * 512;
    const f16* Bblk = Bt + (size_t)colg0 * 512;

    for (int k0 = 0; k0 < 512; k0 += 64) {
        __syncthreads();
#pragma unroll
        for (int i = 0; i < 4; i++) {
            int p = tid + i * 256;           // 16B chunk id
            int m = p >> 3, kc = p & 7;
            int gk = ((kc ^ (m & 7)) << 3);  // XOR-swizzled k origin
            gl2lds16(Ablk + (size_t)m * 512 + k0 + gk, As + p * 8);
            gl2lds16(Bblk + (size_t)m * 512 + k0 + gk, Bs + p * 8);
        }
        __syncthreads();
#pragma unroll
        for (int t = 0; t < 4; t++) {        // four 32x32x16 k-steps
            f16x8 af[2], bfr[2];
#pragma unroll
            for (int bi = 0; bi < 2; bi++) {
                int r = wr * 64 + bi * 32 + nn;
                int ch = r * 8 + ((t * 2 + hh) ^ (r & 7));
                af[bi] = *(const f16x8*)(As + ch * 8);
            }
#pragma unroll
            for (int bj = 0; bj < 2; bj++) {
                int n = wc * 64 + bj * 32 + nn;
                int ch = n * 8 + ((t * 2 + hh) ^ (n & 7));
                bfr[bj] = *(const f16x8*)(Bs + ch * 8);
            }
#pragma unroll
            for (int bi = 0; bi < 2; bi++)
#pragma unroll
                for (int bj = 0; bj < 2; bj++)
                    acc[bi][bj] = __builtin_amdgcn_mfma_f32_32x32x16_f16(
                        af[bi], bfr[bj], acc[bi][bj], 0, 0, 0);
        }
    }

    // C/D mapping (m74/m101): col = nn, rowoff = (reg&3) + 8*(reg>>2) + 4*hh
    if (MODE == 0) {
        const int sel = colg0 >> 9;
        const int c0 = colg0 & 511;
        if (sel < 2) {                      // Q or K: plain row-major
            f16* outp = (sel == 0) ? o0 : o1;
            const float* bp = (sel == 0) ? b0 : b1;
            const float sc = (sel == 0) ? 0.125f : 1.0f;
#pragma unroll
            for (int bj = 0; bj < 2; bj++) {
                int col = c0 + wc * 64 + bj * 32 + nn;
                float bv = bp[col];
#pragma unroll
                for (int bi = 0; bi < 2; bi++)
#pragma unroll
                    for (int rg = 0; rg < 16; rg++) {
                        int row = row0 + wr * 64 + bi * 32 +
                                  (rg & 3) + 8 * (rg >> 2) + 4 * hh;
                        outp[(size_t)row * 512 + col] =
                            (f16)(fmaxf(acc[bi][bj][rg] + bv, 0.f) * sc);
                    }
            }
        } else {                            // V: LDS transpose -> packed V^T tiles
            const int hh_head = c0 >> 6;
            f16 (*T)[136] = (f16(*)[136])smem;   // 64 x 136 fp16
            const int bb = row0 >> 11;
            const int t0 = (row0 & 2047) >> 6;
            __syncthreads();                // all waves done reading As/Bs
#pragma unroll
            for (int ph = 0; ph < 2; ph++) {
                if (wc == ph) {
#pragma unroll
                    for (int bj = 0; bj < 2; bj++) {
                        int d = bj * 32 + nn;
                        float bv = b2[c0 + ph * 64 + d];
#pragma unroll
                        for (int bi = 0; bi < 2; bi++)
#pragma unroll
                            for (int rg = 0; rg < 16; rg++) {
                                int s = wr * 64 + bi * 32 +
                                        (rg & 3) + 8 * (rg >> 2) + 4 * hh;
                                T[d][s] = (f16)fmaxf(acc[bi][bj][rg] + bv, 0.f);
                            }
                    }
                }
                __syncthreads();
#pragma unroll
                for (int ii = 0; ii < 4; ii++) {
                    int oct = tid + ii * 256;        // 1024 octets = 2 tiles
                    int tt = oct >> 9, rem = oct & 511;
                    int d = rem >> 3, s8 = rem & 7;
                    us8 val = *(const us8*)(&T[d][tt * 64 + s8 * 8]);
                    size_t dst = (((size_t)((bb * 8 + hh_head + ph) * 32 + t0 + tt)) << 12)
                                 + d * 64 + s8 * 8;
                    *(us8*)(o2v + dst) = val;
                }
                __syncthreads();
            }
        }
    } else {
#pragma unroll
        for (int bj = 0; bj < 2; bj++) {
            int col = colg0 + wc * 64 + bj * 32 + nn;
            float bv = bias_f[col];
#pragma unroll
            for (int bi = 0; bi < 2; bi++)
#pragma unroll
                for (int rg = 0; rg < 16; rg++) {
                    int row = row0 + wr * 64 + bi * 32 +
                              (rg & 3) + 8 * (rg >> 2) + 4 * hh;
                    ofp[(size_t)row * 512 + col] = fmaxf(acc[bi][bj][rg] + bv, 0.f);
                }
        }
    }
}

// ---- flash attention: 128 queries/block (8 waves share K/V tiles) ----
// R7: R4 structure + (1) per-wave kt-range skip: a wave whose 16 rows'
// groups don't intersect the tile computes only masked zeros
// (exp(-1e9)=0.0f exactly) -> skipping LDS reads+MFMA+softmax for that
// (wave,tile) is bit-identical; staging/barriers stay unconditional,
// branch is wave-uniform. (2) T5 setprio around MFMA clusters (m191).
__global__ __launch_bounds__(512) void attn_mfma(
    const f16* __restrict__ Q, const f16* __restrict__ K,
    const u16* __restrict__ VT, const int* __restrict__ G,
    f16* __restrict__ Y) {
    __shared__ __align__(16) u16 Ks[2][4096];   // frag-image, XOR-swizzled
    __shared__ __align__(16) u16 Vs[2][4096];
    __shared__ int bnd[9];

    const int qt = blockIdx.x, h = blockIdx.y, b = blockIdx.z;
    const int q0 = qt * 128;
    const int tid = threadIdx.x;
    const int w = tid >> 6, lane = tid & 63;
    const int ln = lane & 15, quad = lane >> 4;

    const f16* Qb = Q + (size_t)b * Ssz * Dsz;
    const f16* Kb = K + (size_t)b * Ssz * Dsz;
    const u16* Vtb = VT + (size_t)(b * Hn + h) * 32 * 4096;
    const int* Gb = G + (size_t)b * Ssz;

    // group boundary table (sorted groups): bnd[g] = first i with G[i] >= g
    if (tid < 9) bnd[tid] = Ssz;
    __syncthreads();
    {
        int i0 = tid * 4;                      // 512 threads x 4 = 2048
        int4 gi = *(const int4*)(Gb + i0);
        int gp = (i0 == 0) ? -1 : Gb[i0 - 1];
        int ga[5] = {gp, gi.x, gi.y, gi.z, gi.w};
#pragma unroll
        for (int j = 0; j < 4; j++)
            for (int g = ga[j] + 1; g <= ga[j + 1]; g++) bnd[g] = i0 + j;
    }

    // Q B-frags for 16x16x32 (n=ln, k=quad*8+j), hoisted
    f16x8 qf[2];
    {
        const f16* qrow = Qb + (size_t)(q0 + w * 16 + ln) * Dsz + h * 64;
        qf[0] = *(const f16x8*)(qrow + quad * 8);
        qf[1] = *(const f16x8*)(qrow + 32 + quad * 8);
    }
    const int gq = Gb[q0 + w * 16 + ln];
    const int gqmin = Gb[q0], gqmax = Gb[q0 + 127];
    const int gwmin = Gb[q0 + w * 16];         // this wave's 16 rows
    const int gwmax = Gb[q0 + w * 16 + 15];

    // visited tile range (sorted groups => contiguous)
    int gf = 0, gl = 0; bool ov = false;
    if (lane < 32) {
        gf = Gb[lane * 64]; gl = Gb[lane * 64 + 63];
        ov = (gl >= gqmin) && (gf <= gqmax);
    }
    unsigned long long mask = __ballot(ov);
    const int kt_lo = __builtin_ctzll(mask);
    const int kt_hi = 63 - __builtin_clzll(mask);

    __syncthreads();                         // bnd ready
    const int sq = bnd[gq];
    const unsigned usz = (unsigned)(bnd[gq + 1] - sq);

    f32x4 o[4];
    const f32x4 z4 = {0.f, 0.f, 0.f, 0.f};
#pragma unroll
    for (int nd = 0; nd < 4; nd++) o[nd] = z4;
    float lsum = 0.f;

#define STAGE_K(kt, bi_)                                                       \
    {                                                                          \
        const f16* Ktile = Kb + (size_t)(kt) * 64 * Dsz + h * 64;              \
        int row = tid >> 3, c = tid & 7;                                       \
        gl2lds16(Ktile + (size_t)row * Dsz + ((c ^ (row & 7)) << 3),           \
                 Ks[bi_] + tid * 8);                                           \
    }
#define STAGE_V(kt, bi_)                                                       \
    {                                                                          \
        const u16* Vtile = Vtb + (size_t)(kt) * 4096;                          \
        int row = tid >> 3, c = tid & 7;                                       \
        gl2lds16(Vtile + row * 64 + ((c ^ (row & 7)) << 3),                    \
                 Vs[bi_] + tid * 8);                                           \
    }

    STAGE_K(kt_lo, 0)
    STAGE_V(kt_lo, 0)

    int buf = 0;
    for (int kt = kt_lo; kt <= kt_hi; kt++) {
        __syncthreads();                 // buf ready; all waves off buf^1
        if (kt < kt_hi) { STAGE_K(kt + 1, buf ^ 1) STAGE_V(kt + 1, buf ^ 1) }
        const int gkf = __shfl(gf, kt), gkl = __shfl(gl, kt);
        // per-wave skip: tile's groups vs this wave's rows' groups
        if ((gkl >= gwmin) && (gkf <= gwmax)) {
            const u16* ks = Ks[buf];
            const u16* vs = Vs[buf];
            const int k0 = kt * 64;

            f16x4 pf[4];
#pragma unroll
            for (int kb = 0; kb < 4; kb++) {
                f32x4 s = z4;
                __builtin_amdgcn_s_setprio(1);
#pragma unroll
                for (int kk = 0; kk < 2; kk++) {   // S^T = K Q^T, K=32 per mfma
                    int key = kb * 16 + ln;
                    int ch = key * 8 + ((kk * 4 + quad) ^ (key & 7));
                    f16x8 kf = *(const f16x8*)(ks + ch * 8);
                    s = __builtin_amdgcn_mfma_f32_16x16x32_f16(kf, qf[kk], s, 0, 0, 0);
                }
                __builtin_amdgcn_s_setprio(0);
                const int ckb = k0 + kb * 16 + quad * 4;
                f16x4 pp;
#pragma unroll
                for (int r = 0; r < 4; r++) {
                    float t = s[r] - 4.0f;   // Q pre-scaled; fixed-shift softmax
                    float sval = ((unsigned)(ckb + r - sq) < usz) ? t : -1e9f;
                    float e = __expf(sval);
                    lsum += e;
                    pp[r] = (f16)e;
                }
                pf[kb] = pp;
            }
            // O += P V   (P regs are already the A-operand layout for x16)
            __builtin_amdgcn_s_setprio(1);
#pragma unroll
            for (int nd = 0; nd < 4; nd++)
#pragma unroll
                for (int kc = 0; kc < 4; kc++) {
                    int addr = (((nd * 16 + ln) * 8 +
                                 ((kc * 2 + (quad >> 1)) ^ (ln & 7))) << 3) +
                               (quad & 1) * 4;
                    f16x4 vf = *(const f16x4*)(vs + addr);
                    o[nd] = __builtin_amdgcn_mfma_f32_16x16x16f16(pf[kc], vf, o[nd], 0, 0, 0);
                }
            __builtin_amdgcn_s_setprio(0);
        }
        buf ^= 1;
    }

    lsum += __shfl_xor(lsum, 16);
    lsum += __shfl_xor(lsum, 32);
    float linv = 1.0f / lsum;
#pragma unroll
    for (int r = 0; r < 4; r++) {
        float lr = __shfl(linv, (lane & 48) | (quad * 4 + r));
        size_t row = (size_t)b * Ssz + q0 + w * 16 + quad * 4 + r;
#pragma unroll
        for (int nd = 0; nd < 4; nd++)
            Y[row * Dsz + h * 64 + nd * 16 + ln] = (f16)(o[nd][r] * lr);
    }
#undef STAGE_K
#undef STAGE_V
}

// ============================================================================
// R7: revert R6 fusion (512 agent-scope fences = wbl2/inv storm, attn 97us;
// GLOBAL lesson: per-block device-scope ordering at grid width costs ~100us
// on gfx950 - no cross-block producer/consumer in-kernel). R4 pipeline +
// per-wave kt skip (bit-identical) + setprio in attn. Predicted 141-145us.
// Ledger: fills ~80 fixed, gaps ~29 (4 nodes), kernels: attn 21->~16.5,
// gemm0 ~10, prep ~2, gemm1 ~4.4.
// ============================================================================
extern "C" void kernel_launch(void* const* d_in, const int* in_sizes, int n_in,
                              void* d_out, int out_size, void* d_ws, size_t ws_size,
                              hipStream_t stream) {
    const float* x  = (const float*)d_in[0];
    const int*   g  = (const int*)d_in[1];
    const float* Wq = (const float*)d_in[2];
    const float* bq = (const float*)d_in[3];
    const float* Wk = (const float*)d_in[4];
    const float* bk = (const float*)d_in[5];
    const float* Wv = (const float*)d_in[6];
    const float* bv = (const float*)d_in[7];
    const float* Wo = (const float*)d_in[8];
    const float* bo = (const float*)d_in[9];
    float* out = (float*)d_out;

    const size_t E = (size_t)Bsz * Ssz * Dsz;   // 4M elements
    f16* xb  = (f16*)d_ws;
    f16* qb  = xb + E;                  // [B,S,D] fp16 (Q pre-scaled 0.125)
    f16* kb2 = qb + E;                  // [B,S,D] fp16
    u16* vtb = (u16*)(kb2 + E);         // packed V^T [bh][t][64][64]
    f16* yb  = (f16*)(vtb + E);         // [B,S,D] fp16
    f16* Wtqkv = yb + E;                // [1536][512]
    f16* Wto   = Wtqkv + 1536 * 512;    // [512][512]

    prep<<<2304, 256, 0, stream>>>(x, xb, Wq, Wk, Wv, Wo, Wtqkv, Wto);
    gemm128<0><<<dim3(12, 64), 256, 0, stream>>>(xb, Wtqkv, qb, kb2, vtb,
                                                 bq, bk, bv, nullptr, nullptr);
    attn_mfma<<<dim3(Ssz / 128, Hn, Bsz), 512, 0, stream>>>(qb, kb2, vtb, g, yb);
    gemm128<1><<<dim3(4, 64), 256, 0, stream>>>(yb, Wto, nullptr, nullptr, nullptr,
                                                nullptr, nullptr, nullptr, out, bo);
}

// Round 8
// 143.526 us; speedup vs baseline: 3.3059x; 1.0127x over previous
//
#include <hip/hip_runtime.h>
#include <cmath>

#define Bsz 4
#define Ssz 2048
#define Dsz 512
#define Hn 8

typedef unsigned short u16;
typedef _Float16 f16;
typedef __attribute__((ext_vector_type(4))) _Float16 f16x4;
typedef __attribute__((ext_vector_type(8))) _Float16 f16x8;
typedef __attribute__((ext_vector_type(8))) unsigned short us8;
typedef __attribute__((ext_vector_type(4))) float f32x4;
typedef __attribute__((ext_vector_type(16))) float f32x16;

__device__ __forceinline__ void gl2lds16(const void* g, void* l) {
    __builtin_amdgcn_global_load_lds(
        (const __attribute__((address_space(1))) void*)g,
        (__attribute__((address_space(3))) void*)l, 16, 0, 0);
}

// ---- fused prep: blocks [0,2048) convert x (fp32->fp16, 8/thread);
//      blocks [2048,2304) transpose+convert the 4 weight matrices;
//      block 2304 builds the attn schedule map (anti-correlated pairing):
//      sort 64 (b,qt) tasks by kt-tile count desc; slot s<256 gets rank s,
//      slot s>=256 gets rank 767-s  =>  CU c (blocks c and c+256) gets one
//      long + one short task -> per-CU load equalized. Pure relabeling.
__global__ __launch_bounds__(256) void prep(const float* __restrict__ x,
                                            f16* __restrict__ xb,
                                            const float* __restrict__ Wq,
                                            const float* __restrict__ Wk,
                                            const float* __restrict__ Wv,
                                            const float* __restrict__ Wo,
                                            f16* __restrict__ Wtqkv,
                                            f16* __restrict__ Wto,
                                            const int* __restrict__ gids,
                                            int* __restrict__ smap) {
    const int blk = blockIdx.x;
    const int tid = threadIdx.x;
    if (blk == 2304) {                     // schedule-map builder
        __shared__ int cntS[64];
        __shared__ int rnk[64];
        if (tid < 64) {
            int b = tid >> 4, qt = tid & 15;
            const int* Gb = gids + b * Ssz;
            int gqmin = Gb[qt * 128], gqmax = Gb[qt * 128 + 127];
            int c = 0;
            for (int kt = 0; kt < 32; kt++) {
                int gf = Gb[kt * 64], gl = Gb[kt * 64 + 63];
                c += (gl >= gqmin && gf <= gqmax) ? 1 : 0;
            }
            cntS[tid] = c;
        }
        __syncthreads();
        if (tid < 64) {
            int c = cntS[tid], r = 0;
            for (int j = 0; j < 64; j++) {
                int cj = cntS[j];
                r += ((cj > c) || (cj == c && j < tid)) ? 1 : 0;
            }
            rnk[tid] = r;
        }
        __syncthreads();
        if (tid < 64) {
            int r = rnk[tid];
            int b = tid >> 4, qt = tid & 15;
            int enc = qt | (b << 7);
#pragma unroll
            for (int h = 0; h < 8; h++) {
                int inst = r * 8 + h;
                int slot = (inst < 256) ? inst : 767 - inst;
                smap[slot] = enc | (h << 4);
            }
        }
        return;
    }
    if (blk < 2048) {
        int i = blk * 256 + tid;
        const float4* xv = (const float4*)x;
        float4 a = xv[2 * i], b = xv[2 * i + 1];
        f16x8 o;
        o[0] = (f16)a.x; o[1] = (f16)a.y; o[2] = (f16)a.z; o[3] = (f16)a.w;
        o[4] = (f16)b.x; o[5] = (f16)b.y; o[6] = (f16)b.z; o[7] = (f16)b.w;
        ((f16x8*)xb)[i] = o;
        return;
    }
    __shared__ float T[64][65];
    const int bz = blk - 2048;             // 256 blocks: 8 x 8 x 4
    const int z = bz >> 6;
    const int n0 = (bz & 7) * 64, k0 = ((bz >> 3) & 7) * 64;
    const float* W = (z == 0) ? Wq : (z == 1) ? Wk : (z == 2) ? Wv : Wo;
#pragma unroll
    for (int i = 0; i < 16; i++) {
        int e = tid + i * 256;
        int r = e >> 6, c = e & 63;
        T[r][c] = W[(size_t)(k0 + r) * Dsz + n0 + c];
    }
    __syncthreads();
    f16* dst = (z < 3) ? (Wtqkv + ((size_t)z * 512 + n0) * Dsz + k0)
                       : (Wto + (size_t)n0 * Dsz + k0);
#pragma unroll
    for (int i = 0; i < 16; i++) {
        int e = tid + i * 256;
        int r = e >> 6, c = e & 63;
        dst[(size_t)r * Dsz + c] = (f16)(T[c][r]);
    }
}

// ---- 128x128-tile fp16 MFMA GEMM (32x32x16), C = relu(A @ Bt^T + bias) ----
// MODE 0: Q (x0.125, exact pow2 -> bit-identical attn), K plain,
//         V -> LDS-transposed packed V^T [bh][t][64 d][64 s]. MODE 1: fp32 out.
template <int MODE>
__global__ __launch_bounds__(256) void gemm128(
    const f16* __restrict__ A, const f16* __restrict__ Bt,
    f16* o0, f16* o1, u16* o2v,
    const float* b0, const float* b1, const float* b2,
    float* ofp, const float* bias_f) {
    __shared__ __align__(16) u16 smem[2 * 128 * 64];   // As | Bs ; reused as T
    u16* As = smem;
    u16* Bs = smem + 128 * 64;
    const int tid = threadIdx.x;
    const int colg0 = blockIdx.x * 128;
    const int row0 = blockIdx.y * 128;
    const int w = tid >> 6, lane = tid & 63;
    const int nn = lane & 31, hh = lane >> 5;
    const int wr = w >> 1, wc = w & 1;

    f32x16 acc[2][2];
#pragma unroll
    for (int bi = 0; bi < 2; bi++)
#pragma unroll
        for (int bj = 0; bj < 2; bj++)
#pragma unroll
            for (int e = 0; e < 16; e++) acc[bi][bj][e] = 0.f;

    const f16* Ablk = A + (size_t)row0 * 512;
    const f16* Bblk = Bt + (size_t)colg0 * 512;

    for (int k0 = 0; k0 < 512; k0 += 64) {
        __syncthreads();
#pragma unroll
        for (int i = 0; i < 4; i++) {
            int p = tid + i * 256;           // 16B chunk id
            int m = p >> 3, kc = p & 7;
            int gk = ((kc ^ (m & 7)) << 3);  // XOR-swizzled k origin
            gl2lds16(Ablk + (size_t)m * 512 + k0 + gk, As + p * 8);
            gl2lds16(Bblk + (size_t)m * 512 + k0 + gk, Bs + p * 8);
        }
        __syncthreads();
#pragma unroll
        for (int t = 0; t < 4; t++) {        // four 32x32x16 k-steps
            f16x8 af[2], bfr[2];
#pragma unroll
            for (int bi = 0; bi < 2; bi++) {
                int r = wr * 64 + bi * 32 + nn;
                int ch = r * 8 + ((t * 2 + hh) ^ (r & 7));
                af[bi] = *(const f16x8*)(As + ch * 8);
            }
#pragma unroll
            for (int bj = 0; bj < 2; bj++) {
                int n = wc * 64 + bj * 32 + nn;
                int ch = n * 8 + ((t * 2 + hh) ^ (n & 7));
                bfr[bj] = *(const f16x8*)(Bs + ch * 8);
            }
#pragma unroll
            for (int bi = 0; bi < 2; bi++)
#pragma unroll
                for (int bj = 0; bj < 2; bj++)
                    acc[bi][bj] = __builtin_amdgcn_mfma_f32_32x32x16_f16(
                        af[bi], bfr[bj], acc[bi][bj], 0, 0, 0);
        }
    }

    // C/D mapping (m74/m101): col = nn, rowoff = (reg&3) + 8*(reg>>2) + 4*hh
    if (MODE == 0) {
        const int sel = colg0 >> 9;
        const int c0 = colg0 & 511;
        if (sel < 2) {                      // Q or K: plain row-major
            f16* outp = (sel == 0) ? o0 : o1;
            const float* bp = (sel == 0) ? b0 : b1;
            const float sc = (sel == 0) ? 0.125f : 1.0f;
#pragma unroll
            for (int bj = 0; bj < 2; bj++) {
                int col = c0 + wc * 64 + bj * 32 + nn;
                float bv = bp[col];
#pragma unroll
                for (int bi = 0; bi < 2; bi++)
#pragma unroll
                    for (int rg = 0; rg < 16; rg++) {
                        int row = row0 + wr * 64 + bi * 32 +
                                  (rg & 3) + 8 * (rg >> 2) + 4 * hh;
                        outp[(size_t)row * 512 + col] =
                            (f16)(fmaxf(acc[bi][bj][rg] + bv, 0.f) * sc);
                    }
            }
        } else {                            // V: LDS transpose -> packed V^T tiles
            const int hh_head = c0 >> 6;
            f16 (*T)[136] = (f16(*)[136])smem;   // 64 x 136 fp16
            const int bb = row0 >> 11;
            const int t0 = (row0 & 2047) >> 6;
            __syncthreads();                // all waves done reading As/Bs
#pragma unroll
            for (int ph = 0; ph < 2; ph++) {
                if (wc == ph) {
#pragma unroll
                    for (int bj = 0; bj < 2; bj++) {
                        int d = bj * 32 + nn;
                        float bv = b2[c0 + ph * 64 + d];
#pragma unroll
                        for (int bi = 0; bi < 2; bi++)
#pragma unroll
                            for (int rg = 0; rg < 16; rg++) {
                                int s = wr * 64 + bi * 32 +
                                        (rg & 3) + 8 * (rg >> 2) + 4 * hh;
                                T[d][s] = (f16)fmaxf(acc[bi][bj][rg] + bv, 0.f);
                            }
                    }
                }
                __syncthreads();
#pragma unroll
                for (int ii = 0; ii < 4; ii++) {
                    int oct = tid + ii * 256;        // 1024 octets = 2 tiles
                    int tt = oct >> 9, rem = oct & 511;
                    int d = rem >> 3, s8 = rem & 7;
                    us8 val = *(const us8*)(&T[d][tt * 64 + s8 * 8]);
                    size_t dst = (((size_t)((bb * 8 + hh_head + ph) * 32 + t0 + tt)) << 12)
                                 + d * 64 + s8 * 8;
                    *(us8*)(o2v + dst) = val;
                }
                __syncthreads();
            }
        }
    } else {
#pragma unroll
        for (int bj = 0; bj < 2; bj++) {
            int col = colg0 + wc * 64 + bj * 32 + nn;
            float bv = bias_f[col];
#pragma unroll
            for (int bi = 0; bi < 2; bi++)
#pragma unroll
                for (int rg = 0; rg < 16; rg++) {
                    int row = row0 + wr * 64 + bi * 32 +
                              (rg & 3) + 8 * (rg >> 2) + 4 * hh;
                    ofp[(size_t)row * 512 + col] = fmaxf(acc[bi][bj][rg] + bv, 0.f);
                }
        }
    }
}

// ---- flash attention: 128 queries/block (8 waves share K/V tiles) ----
// R8: R7 body; block identity from schedule map (anti-correlated pairing).
// Pure blockIdx relabeling -> bit-identical output.
__global__ __launch_bounds__(512) void attn_mfma(
    const f16* __restrict__ Q, const f16* __restrict__ K,
    const u16* __restrict__ VT, const int* __restrict__ G,
    f16* __restrict__ Y, const int* __restrict__ smap) {
    __shared__ __align__(16) u16 Ks[2][4096];   // frag-image, XOR-swizzled
    __shared__ __align__(16) u16 Vs[2][4096];
    __shared__ int bnd[9];

    const int m = smap[blockIdx.x];
    const int qt = m & 15, h = (m >> 4) & 7, b = (m >> 7) & 3;
    const int q0 = qt * 128;
    const int tid = threadIdx.x;
    const int w = tid >> 6, lane = tid & 63;
    const int ln = lane & 15, quad = lane >> 4;

    const f16* Qb = Q + (size_t)b * Ssz * Dsz;
    const f16* Kb = K + (size_t)b * Ssz * Dsz;
    const u16* Vtb = VT + (size_t)(b * Hn + h) * 32 * 4096;
    const int* Gb = G + (size_t)b * Ssz;

    // group boundary table (sorted groups): bnd[g] = first i with G[i] >= g
    if (tid < 9) bnd[tid] = Ssz;
    __syncthreads();
    {
        int i0 = tid * 4;                      // 512 threads x 4 = 2048
        int4 gi = *(const int4*)(Gb + i0);
        int gp = (i0 == 0) ? -1 : Gb[i0 - 1];
        int ga[5] = {gp, gi.x, gi.y, gi.z, gi.w};
#pragma unroll
        for (int j = 0; j < 4; j++)
            for (int g = ga[j] + 1; g <= ga[j + 1]; g++) bnd[g] = i0 + j;
    }

    // Q B-frags for 16x16x32 (n=ln, k=quad*8+j), hoisted
    f16x8 qf[2];
    {
        const f16* qrow = Qb + (size_t)(q0 + w * 16 + ln) * Dsz + h * 64;
        qf[0] = *(const f16x8*)(qrow + quad * 8);
        qf[1] = *(const f16x8*)(qrow + 32 + quad * 8);
    }
    const int gq = Gb[q0 + w * 16 + ln];
    const int gqmin = Gb[q0], gqmax = Gb[q0 + 127];
    const int gwmin = Gb[q0 + w * 16];         // this wave's 16 rows
    const int gwmax = Gb[q0 + w * 16 + 15];

    // visited tile range (sorted groups => contiguous)
    int gf = 0, gl = 0; bool ov = false;
    if (lane < 32) {
        gf = Gb[lane * 64]; gl = Gb[lane * 64 + 63];
        ov = (gl >= gqmin) && (gf <= gqmax);
    }
    unsigned long long mask = __ballot(ov);
    const int kt_lo = __builtin_ctzll(mask);
    const int kt_hi = 63 - __builtin_clzll(mask);

    __syncthreads();                         // bnd ready
    const int sq = bnd[gq];
    const unsigned usz = (unsigned)(bnd[gq + 1] - sq);

    f32x4 o[4];
    const f32x4 z4 = {0.f, 0.f, 0.f, 0.f};
#pragma unroll
    for (int nd = 0; nd < 4; nd++) o[nd] = z4;
    float lsum = 0.f;

#define STAGE_K(kt, bi_)                                                       \
    {                                                                          \
        const f16* Ktile = Kb + (size_t)(kt) * 64 * Dsz + h * 64;              \
        int row = tid >> 3, c = tid & 7;                                       \
        gl2lds16(Ktile + (size_t)row * Dsz + ((c ^ (row & 7)) << 3),           \
                 Ks[bi_] + tid * 8);                                           \
    }
#define STAGE_V(kt, bi_)                                                       \
    {                                                                          \
        const u16* Vtile = Vtb + (size_t)(kt) * 4096;                          \
        int row = tid >> 3, c = tid & 7;                                       \
        gl2lds16(Vtile + row * 64 + ((c ^ (row & 7)) << 3),                    \
                 Vs[bi_] + tid * 8);                                           \
    }

    STAGE_K(kt_lo, 0)
    STAGE_V(kt_lo, 0)

    int buf = 0;
    for (int kt = kt_lo; kt <= kt_hi; kt++) {
        __syncthreads();                 // buf ready; all waves off buf^1
        if (kt < kt_hi) { STAGE_K(kt + 1, buf ^ 1) STAGE_V(kt + 1, buf ^ 1) }
        const int gkf = __shfl(gf, kt), gkl = __shfl(gl, kt);
        // per-wave skip: tile's groups vs this wave's rows' groups
        if ((gkl >= gwmin) && (gkf <= gwmax)) {
            const u16* ks = Ks[buf];
            const u16* vs = Vs[buf];
            const int k0 = kt * 64;

            f16x4 pf[4];
#pragma unroll
            for (int kb = 0; kb < 4; kb++) {
                f32x4 s = z4;
                __builtin_amdgcn_s_setprio(1);
#pragma unroll
                for (int kk = 0; kk < 2; kk++) {   // S^T = K Q^T, K=32 per mfma
                    int key = kb * 16 + ln;
                    int ch = key * 8 + ((kk * 4 + quad) ^ (key & 7));
                    f16x8 kf = *(const f16x8*)(ks + ch * 8);
                    s = __builtin_amdgcn_mfma_f32_16x16x32_f16(kf, qf[kk], s, 0, 0, 0);
                }
                __builtin_amdgcn_s_setprio(0);
                const int ckb = k0 + kb * 16 + quad * 4;
                f16x4 pp;
#pragma unroll
                for (int r = 0; r < 4; r++) {
                    float t = s[r] - 4.0f;   // Q pre-scaled; fixed-shift softmax
                    float sval = ((unsigned)(ckb + r - sq) < usz) ? t : -1e9f;
                    float e = __expf(sval);
                    lsum += e;
                    pp[r] = (f16)e;
                }
                pf[kb] = pp;
            }
            // O += P V   (P regs are already the A-operand layout for x16)
            __builtin_amdgcn_s_setprio(1);
#pragma unroll
            for (int nd = 0; nd < 4; nd++)
#pragma unroll
                for (int kc = 0; kc < 4; kc++) {
                    int addr = (((nd * 16 + ln) * 8 +
                                 ((kc * 2 + (quad >> 1)) ^ (ln & 7))) << 3) +
                               (quad & 1) * 4;
                    f16x4 vf = *(const f16x4*)(vs + addr);
                    o[nd] = __builtin_amdgcn_mfma_f32_16x16x16f16(pf[kc], vf, o[nd], 0, 0, 0);
                }
            __builtin_amdgcn_s_setprio(0);
        }
        buf ^= 1;
    }

    lsum += __shfl_xor(lsum, 16);
    lsum += __shfl_xor(lsum, 32);
    float linv = 1.0f / lsum;
#pragma unroll
    for (int r = 0; r < 4; r++) {
        float lr = __shfl(linv, (lane & 48) | (quad * 4 + r));
        size_t row = (size_t)b * Ssz + q0 + w * 16 + quad * 4 + r;
#pragma unroll
        for (int nd = 0; nd < 4; nd++)
            Y[row * Dsz + h * 64 + nd * 16 + ln] = (f16)(o[nd][r] * lr);
    }
#undef STAGE_K
#undef STAGE_V
}

// ============================================================================
// R8: R7 + anti-correlated task pairing for attn. All 512 attn blocks are
// co-resident (2/CU) from t=0, so the tail = variance of per-CU PAIR sums;
// dispatch round-robins CUs (blocks s and s+256 share a CU), so sorting tasks
// by kt-count and pairing rank s with rank 511-s equalizes per-CU load.
// Relabeling only -> bit-identical. Predicted 141-144.5us (attn 18.7->~15.7).
// Neutral if CU-assignment heuristic wrong (no downside).
// Ledger: fills ~80 fixed, gaps ~29.6, kernels: attn ~15.7, gemm0 ~10.5,
// gemm1 ~4.4, prep ~1.8. R5/R6 lesson: no in-kernel cross-block sync.
// ============================================================================
extern "C" void kernel_launch(void* const* d_in, const int* in_sizes, int n_in,
                              void* d_out, int out_size, void* d_ws, size_t ws_size,
                              hipStream_t stream) {
    const float* x  = (const float*)d_in[0];
    const int*   g  = (const int*)d_in[1];
    const float* Wq = (const float*)d_in[2];
    const float* bq = (const float*)d_in[3];
    const float* Wk = (const float*)d_in[4];
    const float* bk = (const float*)d_in[5];
    const float* Wv = (const float*)d_in[6];
    const float* bv = (const float*)d_in[7];
    const float* Wo = (const float*)d_in[8];
    const float* bo = (const float*)d_in[9];
    float* out = (float*)d_out;

    const size_t E = (size_t)Bsz * Ssz * Dsz;   // 4M elements
    f16* xb  = (f16*)d_ws;
    f16* qb  = xb + E;                  // [B,S,D] fp16 (Q pre-scaled 0.125)
    f16* kb2 = qb + E;                  // [B,S,D] fp16
    u16* vtb = (u16*)(kb2 + E);         // packed V^T [bh][t][64][64]
    f16* yb  = (f16*)(vtb + E);         // [B,S,D] fp16
    f16* Wtqkv = yb + E;                // [1536][512]
    f16* Wto   = Wtqkv + 1536 * 512;    // [512][512]
    int* smap  = (int*)(Wto + 512 * 512);   // 512-entry attn schedule map

    prep<<<2305, 256, 0, stream>>>(x, xb, Wq, Wk, Wv, Wo, Wtqkv, Wto, g, smap);
    gemm128<0><<<dim3(12, 64), 256, 0, stream>>>(xb, Wtqkv, qb, kb2, vtb,
                                                 bq, bk, bv, nullptr, nullptr);
    attn_mfma<<<dim3(512), 512, 0, stream>>>(qb, kb2, vtb, g, yb, smap);
    gemm128<1><<<dim3(4, 64), 256, 0, stream>>>(yb, Wto, nullptr, nullptr, nullptr,
                                                nullptr, nullptr, nullptr, out, bo);
}